// Round 1
// baseline (248.839 us; speedup 1.0000x reference)
//
#include <hip/hip_runtime.h>

// HexConv2d implicit GEMM, bf16 MFMA 16x16x32.
// v7: wave decomposition 4x(64och x 160px) acc[4][10] -> 4x(128och x 80px)
// acc[8][5]. Same 160 AGPR, same 2240 MFMA/wave, but each ds_read_b128 B-frag
// now feeds 8 MFMAs (was 4): per-CU ds_read count halves (4480->2240, LDS pipe
// 54k->27k cyc vs 83k MFMA floor) and each read's latency is covered by ~148
// cyc of MFMA pipe work. A-frag (weight) L2 loads double per wave (still only
// ~22 B/cyc of 56 B/cyc per-CU L2). s_setprio(1) around each 40-MFMA cluster.
// Everything else (PT=160, grid 16x32 = 2 blocks/CU, 2-kc double-buffered
// global_load_lds staging, pitch-50 padded pixel space, prep kernels) is
// unchanged from v6 (79.1 us, MfmaUtil 39%, 0 bank conflicts).

typedef __attribute__((ext_vector_type(8))) short short8;
typedef __attribute__((ext_vector_type(4))) short short4v;
typedef __attribute__((ext_vector_type(4))) float floatx4;

#define NPIX   2401
#define W50    50
#define PREAL  2450      // 49 rows * 50
#define XBLEAD 56
#define XBROWS 2672      // padded rows per batch: [-56, 2616)
#define PT6    160       // pixels per block
#define NT6    16        // 16*160 = 2560 >= 2450 ; grid 16x32 = 512 = 2/CU exactly
#define NSEG6  17        // 272 window rows: [P0-56, P0+216)
#define BUF6   (2*NSEG6*1024)                 // 34816 B per buffer (2 kc)
#define XB3_BYTES ((size_t)32*XBROWS*256*2)   // 43,778,048
#define WP_BYTES  917504ULL
#define WS_NEED3  (XB3_BYTES + WP_BYTES)
#define NPADROW 271      // 56 apron + 49 col-49 + 166 tail rows per batch

__device__ __forceinline__ unsigned short f2bf(float f) {
  unsigned u = __builtin_bit_cast(unsigned, f);
  u += 0x7fffu + ((u >> 16) & 1u);          // RNE
  return (unsigned short)(u >> 16);
}

// ---------------- prep: W[o,c,n] fp32 -> bf16 MFMA-A fragment order ----------------
// frag f = ((n*8+kc)*16+ot): lane l holds 8 bf16: W[ot*16+(l&15)][kc*32+(l>>4)*8+j][n]
__global__ void prep_w_kernel(const float* __restrict__ w, unsigned short* __restrict__ wp) {
  int t = blockIdx.x * 256 + threadIdx.x;   // 0..57343
  int l  = t & 63;
  int ot = (t >> 6) & 15;
  int kc = (t >> 10) & 7;
  int n  = t >> 13;
  int o  = ot * 16 + (l & 15);
  int cb = kc * 32 + ((l >> 4) * 8);
  const float* src = w + (size_t)(o * 256 + cb) * 7 + n;
  short8 pk;
#pragma unroll
  for (int j = 0; j < 8; ++j) pk[j] = (short)f2bf(src[j * 7]);
  ((short8*)wp)[t] = pk;
}

// ---------------- prep: zero only the pad rows of xb (compact) ----------------
__global__ void zero_pads5(unsigned short* __restrict__ xb) {
  int idx = blockIdx.x * 256 + threadIdx.x;   // 32*271*32 = 277,504 threads
  if (idx >= 32 * NPADROW * 32) return;
  int c16 = idx & 31;
  int rr  = idx >> 5;
  int pr  = rr % NPADROW;
  int b   = rr / NPADROW;
  int row;
  if (pr < 56)        row = pr;                          // leading apron
  else if (pr < 105)  row = 105 + 50 * (pr - 56);        // col-49 pad rows
  else                row = 2506 + (pr - 105);           // trailing apron
  short8 z = {0,0,0,0,0,0,0,0};
  *(short8*)(xb + ((size_t)b * XBROWS + row) * 256 + c16 * 8) = z;
}

// ---------------- prep: x [b][c][2401] fp32 -> xb [b][row][256c] bf16 (masked) ------
__global__ __launch_bounds__(256)
void prep_x4(const float* __restrict__ x, unsigned short* __restrict__ xb) {
  __shared__ unsigned short t[64][68];      // [ch_local][pix_local]
  const int tid = threadIdx.x;
  const int span = blockIdx.x, cg = blockIdx.y, b = blockIdx.z;
  const int s0 = span * 64;
  {
    const int chl = tid >> 2, i4 = tid & 3;
    const float* src = x + ((size_t)(b * 256 + cg * 64 + chl)) * NPIX;
    const int rbase = s0 + i4 * 16;
#pragma unroll
    for (int it = 0; it < 4; ++it) {
      int r = rbase + it * 4;
      float vv[4] = {0.f, 0.f, 0.f, 0.f};
      if (r + 3 < NPIX) {
        float4 v = *(const float4*)(src + r);
        vv[0] = v.x; vv[1] = v.y; vv[2] = v.z; vv[3] = v.w;
      } else {
#pragma unroll
        for (int e = 0; e < 4; ++e) if (r + e < NPIX) vv[e] = src[r + e];
      }
      short4v u = {0, 0, 0, 0};
#pragma unroll
      for (int e = 0; e < 4; ++e) {
        int re = r + e;
        unsigned short uu = 0;
        if (re < NPIX) {
          int h = re / 49, w = re - h * 49, s = h + w;
          if (s >= 24 && s <= 72) uu = f2bf(vv[e]);
        }
        u[e] = (short)uu;
      }
      *(short4v*)&t[chl][i4 * 16 + it * 4] = u;
    }
  }
  __syncthreads();
  const int pp = tid >> 3;   // pixel pair 0..31
  const int co = tid & 7;    // channel octet 0..7
  unsigned d[8];
#pragma unroll
  for (int k = 0; k < 8; ++k) d[k] = *(const unsigned*)&t[co * 8 + k][pp * 2];
  uint4 lo, hi;
  {
    unsigned l0[4], h0[4];
#pragma unroll
    for (int m = 0; m < 4; ++m) {
      unsigned a = d[2 * m], bq = d[2 * m + 1];
      l0[m] = (a & 0xffffu) | (bq << 16);
      h0[m] = (a >> 16) | (bq & 0xffff0000u);
    }
    lo = make_uint4(l0[0], l0[1], l0[2], l0[3]);
    hi = make_uint4(h0[0], h0[1], h0[2], h0[3]);
  }
  const int r_lo = s0 + pp * 2, r_hi = r_lo + 1;
  if (r_lo < NPIX) {
    int prow = r_lo + r_lo / 49 + XBLEAD;
    *(uint4*)(xb + ((size_t)b * XBROWS + prow) * 256 + cg * 64 + co * 8) = lo;
  }
  if (r_hi < NPIX) {
    int prow = r_hi + r_hi / 49 + XBLEAD;
    *(uint4*)(xb + ((size_t)b * XBROWS + prow) * 256 + cg * 64 + co * 8) = hi;
  }
}

// ---------------- main v7 ----------------
__global__ __launch_bounds__(256, 2)
void hexconv_v7(const unsigned short* __restrict__ xb,
                const unsigned short* __restrict__ wp,
                const float* __restrict__ bias,
                float* __restrict__ out) {
  __shared__ __attribute__((aligned(16))) unsigned char smem[2 * BUF6];  // 69632 B

  const int tid  = threadIdx.x;
  const int lane = tid & 63;
  const int wv   = tid >> 6;
  const int col  = lane & 15;
  const int quad = lane >> 4;

  // wave -> (och half, px half): oh owns 128 out-channels, ph owns 80 pixels
  const int oh = wv >> 1;            // 0..1
  const int ph = wv & 1;             // 0..1

  const int pt = blockIdx.x;          // 0..15
  const int b  = blockIdx.y;
  const int P0 = pt * PT6;
  const int phase = ((pt + b) & 3) * 2;

  // tap offsets in pitch-50 padded space
  const int OFF[7] = {0, 50, 1, -49, -50, -1, 49};

  // B-frag LDS base addresses (kc/j-invariant; j adds j*1024 = 16 rows)
  int ba[7];
#pragma unroll
  for (int n = 0; n < 7; ++n) {
    int r0 = col + 56 + OFF[n];              // 6..121
    int r64 = r0 << 6;
    ba[n] = (r64 + quad * 16) ^ ((r64 >> 3) & 0x30);
  }

  // staging: within a seg, lane l covers row 16s+(l>>2), LDS part l&3 (HW-forced),
  // global part swizzled so compute-side XOR lands conflict-free
  const int gpart = (lane & 3) ^ ((lane >> 3) & 3);
  const char* gsrc0 = (const char*)(xb + ((size_t)b * XBROWS + (size_t)P0) * 256)
                      + (lane >> 2) * 512 + gpart * 16;

  // stage 2 kc into one buffer: 34 seg-units split over 4 waves
  auto stage2 = [&](int buf, int kc0) {
    char* ldsb = (char*)smem + buf * BUF6;
    for (int u = wv; u < 2 * NSEG6; u += 4) {
      int kk = (u >= NSEG6) ? 1 : 0;
      int s  = u - kk * NSEG6;
      __builtin_amdgcn_global_load_lds(
          (const __attribute__((address_space(1))) unsigned int*)
              (gsrc0 + (size_t)s * 8192 + (kc0 + kk) * 64),
          (__attribute__((address_space(3))) unsigned int*)(ldsb + u * 1024), 16, 0, 0);
    }
  };

  // A-frag base: this wave's 8 och tiles start at ot = oh*8
  const char* wbase = (const char*)wp + (size_t)(oh * 8) * 1024 + lane * 16;

  floatx4 acc[8][5];
#pragma unroll
  for (int ii = 0; ii < 8; ++ii)
#pragma unroll
    for (int j = 0; j < 5; ++j) acc[ii][j] = (floatx4){0.f, 0.f, 0.f, 0.f};

  stage2(0, phase);
  __syncthreads();

  for (int i = 0; i < 4; ++i) {
    const int kc0  = (2 * i + phase) & 7;
    const int kc0n = (2 * i + 2 + phase) & 7;
    if (i < 3) stage2((i + 1) & 1, kc0n);
    const char* bufp = (const char*)smem + (i & 1) * BUF6;
#pragma unroll
    for (int n = 0; n < 7; ++n) {
#pragma unroll
      for (int kk = 0; kk < 2; ++kk) {
        const int kc = kc0 + kk;
        short8 af[8];
#pragma unroll
        for (int ii = 0; ii < 8; ++ii)
          af[ii] = *(const short8*)(wbase + ((size_t)((n * 8 + kc) * 16 + ii)) * 1024);
        const char* bp = bufp + kk * (NSEG6 * 1024) + ba[n];
        short8 bfv[5];
#pragma unroll
        for (int j = 0; j < 5; ++j)
          bfv[j] = *(const short8*)(bp + (size_t)(ph * 5 + j) * 1024);
        __builtin_amdgcn_s_setprio(1);
#pragma unroll
        for (int j = 0; j < 5; ++j)
#pragma unroll
          for (int ii = 0; ii < 8; ++ii)
            acc[ii][j] = __builtin_amdgcn_mfma_f32_16x16x32_bf16(af[ii], bfv[j], acc[ii][j], 0, 0, 0);
        __builtin_amdgcn_s_setprio(0);
      }
    }
    if (i < 3) __syncthreads();
  }

  // epilogue: D[row=quad*4+rr][col]; o = oh*128+ii*16+quad*4+rr,
  // padded pix = P0 + ph*80 + j*16 + col
  const int ob = oh * 128;
  floatx4 bv[8];
#pragma unroll
  for (int ii = 0; ii < 8; ++ii)
    bv[ii] = *(const floatx4*)(bias + ob + ii * 16 + quad * 4);

#pragma unroll
  for (int j = 0; j < 5; ++j) {
    int p = P0 + ph * 80 + j * 16 + col;
    int h = p / W50;
    int w = p - h * W50;
    if (w >= 49 || p >= PREAL) continue;
    bool m = (h + w >= 24) && (h + w <= 72);
    size_t ridx = (size_t)h * 49 + w;
#pragma unroll
    for (int ii = 0; ii < 8; ++ii) {
      float* dst = out + ((size_t)(b * 256 + ob + ii * 16 + quad * 4)) * NPIX + ridx;
#pragma unroll
      for (int rr = 0; rr < 4; ++rr) {
        float v = m ? (acc[ii][j][rr] + bv[ii][rr]) : 0.f;
        dst[(size_t)rr * NPIX] = v;
      }
    }
  }
}

// ---------------- fallback v1 (ws too small) ----------------
#define PITCH  40
#define V1WIN  168
#define V1ZROW 168
__global__ __launch_bounds__(256)
void hexconv_v1(const float* __restrict__ x,
                const unsigned short* __restrict__ wp,
                const float* __restrict__ bias,
                float* __restrict__ out) {
  __shared__ unsigned short sm[(V1ZROW + 2) * PITCH];
  const int tid = threadIdx.x, lane = tid & 63, wv = tid >> 6;
  const int col = lane & 15, quad = lane >> 4;
  const int pt = blockIdx.x, b = blockIdx.y;
  const int P0 = pt * 64, win_start = P0 - 52;
  if (tid < PITCH * 2) sm[V1ZROW * PITCH + tid] = 0;
  const int OFF[7] = {0, 49, 1, -48, -49, -1, 48};
  const int DXP = (1 << 2) | (1 << 3), DXN = (1 << 5) | (1 << 6);
  int baddr[4][7];
#pragma unroll
  for (int j = 0; j < 4; ++j) {
    int pix = P0 + j * 16 + col;
    int wj = pix % 49;
    int rowbase = pix - win_start;
#pragma unroll
    for (int n = 0; n < 7; ++n) {
      bool bad = (((DXP >> n) & 1) && wj == 48) || (((DXN >> n) & 1) && wj == 0);
      int row = bad ? V1ZROW : (rowbase + OFF[n]);
      baddr[j][n] = row * (PITCH * 2) + quad * 16;
    }
  }
  int sp[3], sgp[3]; bool sok[3];
#pragma unroll
  for (int pi = 0; pi < 3; ++pi) {
    int p = lane + pi * 64, gp = win_start + p;
    sp[pi] = p; sgp[pi] = gp;
    bool hm = false;
    if (gp >= 0 && gp < NPIX) { int h = gp / 49, w = gp - h * 49, s = h + w; hm = (s >= 24 && s <= 72); }
    sok[pi] = (p < V1WIN) && hm;
  }
  floatx4 acc[4][4];
#pragma unroll
  for (int i = 0; i < 4; ++i)
#pragma unroll
    for (int j = 0; j < 4; ++j) acc[i][j] = (floatx4){0.f, 0.f, 0.f, 0.f};
  const short8* wpv = (const short8*)wp;
  const int wslot = wv * 4;
  for (int kc = 0; kc < 8; ++kc) {
    __syncthreads();
#pragma unroll
    for (int ci = 0; ci < 8; ++ci) {
      int c = ci * 4 + wv;
      const float* src = x + ((size_t)(b * 256 + kc * 32 + c)) * NPIX;
#pragma unroll
      for (int pi = 0; pi < 3; ++pi) {
        if (sp[pi] < V1WIN) {
          float v = sok[pi] ? src[sgp[pi]] : 0.f;
          sm[sp[pi] * PITCH + c] = f2bf(v);
        }
      }
    }
    __syncthreads();
#pragma unroll
    for (int n = 0; n < 7; ++n) {
      short8 af[4];
#pragma unroll
      for (int i = 0; i < 4; ++i)
        af[i] = wpv[((size_t)((n * 8 + kc) * 16 + wslot + i)) * 64 + lane];
      short8 bf[4];
#pragma unroll
      for (int j = 0; j < 4; ++j)
        bf[j] = *(const short8*)((const char*)sm + baddr[j][n]);
#pragma unroll
      for (int i = 0; i < 4; ++i)
#pragma unroll
        for (int j = 0; j < 4; ++j)
          acc[i][j] = __builtin_amdgcn_mfma_f32_16x16x32_bf16(af[i], bf[j], acc[i][j], 0, 0, 0);
    }
  }
  const int ob = wv * 64;
  floatx4 bv[4];
#pragma unroll
  for (int i = 0; i < 4; ++i)
    bv[i] = *(const floatx4*)(bias + ob + i * 16 + quad * 4);
#pragma unroll
  for (int j = 0; j < 4; ++j) {
    int pix = P0 + j * 16 + col;
    if (pix >= NPIX) continue;
    int h = pix / 49, w = pix - h * 49;
    bool m = (h + w >= 24 && h + w <= 72);
#pragma unroll
    for (int i = 0; i < 4; ++i) {
      int o = ob + i * 16 + quad * 4;
      float* dst = out + ((size_t)(b * 256 + o)) * NPIX + pix;
#pragma unroll
      for (int r = 0; r < 4; ++r) {
        float v = m ? (acc[i][j][r] + bv[i][r]) : 0.f;
        dst[(size_t)r * NPIX] = v;
      }
    }
  }
}

extern "C" void kernel_launch(void* const* d_in, const int* in_sizes, int n_in,
                              void* d_out, int out_size, void* d_ws, size_t ws_size,
                              hipStream_t stream) {
  const float* x    = (const float*)d_in[0];   // [32,256,49,49]
  const float* w    = (const float*)d_in[1];   // [256,256,7]
  const float* bias = (const float*)d_in[2];   // [256]
  float* out = (float*)d_out;

  if (ws_size >= WS_NEED3) {
    unsigned short* xb = (unsigned short*)d_ws;
    unsigned short* wp = (unsigned short*)((char*)d_ws + XB3_BYTES);
    zero_pads5<<<(32 * NPADROW * 32 + 255) / 256, 256, 0, stream>>>(xb);
    prep_w_kernel<<<224, 256, 0, stream>>>(w, wp);
    prep_x4<<<dim3(38, 4, 32), 256, 0, stream>>>(x, xb);
    hexconv_v7<<<dim3(NT6, 32), 256, 0, stream>>>(xb, wp, bias, out);
  } else {
    unsigned short* wp = (unsigned short*)d_ws;
    prep_w_kernel<<<224, 256, 0, stream>>>(w, wp);
    hexconv_v1<<<dim3(38, 32), 256, 0, stream>>>(x, wp, bias, out);
  }
}

// Round 2
// 229.514 us; speedup vs baseline: 1.0842x; 1.0842x over previous
//
#include <hip/hip_runtime.h>

// HexConv2d implicit GEMM, bf16 MFMA 16x16x32.
// v8: revert to v6 decomposition (4 waves x (64och x 160px), acc[4][10], af[4])
// and attack OCCUPANCY. Evidence: v6 VGPR_Count=104 arch + 160 acc = 264 > 256
// unified regs -> only 1 wave/SIMD resident (occupancy ~17% ~= 12.5% + ramp),
// confirmed by v7 (+20 VGPR, occupancy unchanged 16.7%). Shave arch regs to
// <= 96 so 2 blocks/CU genuinely fit:
//   (a) ba[7] loop-invariant LDS addrs packed as 16-bit pairs into pk[4]
//   (b) bias pre-added into acc (bv regs die before store-loop addressing)
//   (c) 32-bit epilogue index math (max idx 20.3M < 2^31)
// Everything else identical to v6 (79.1 us, MfmaUtil 40%, 0 bank conflicts).

typedef __attribute__((ext_vector_type(8))) short short8;
typedef __attribute__((ext_vector_type(4))) short short4v;
typedef __attribute__((ext_vector_type(4))) float floatx4;

#define NPIX   2401
#define W50    50
#define PREAL  2450      // 49 rows * 50
#define XBLEAD 56
#define XBROWS 2672      // padded rows per batch: [-56, 2616)
#define PT6    160       // pixels per block
#define NT6    16        // 16*160 = 2560 >= 2450 ; grid 16x32 = 512 = 2/CU exactly
#define NSEG6  17        // 272 window rows: [P0-56, P0+216)
#define BUF6   (2*NSEG6*1024)                 // 34816 B per buffer (2 kc)
#define XB3_BYTES ((size_t)32*XBROWS*256*2)   // 43,778,048
#define WP_BYTES  917504ULL
#define WS_NEED3  (XB3_BYTES + WP_BYTES)
#define NPADROW 271      // 56 apron + 49 col-49 + 166 tail rows per batch

__device__ __forceinline__ unsigned short f2bf(float f) {
  unsigned u = __builtin_bit_cast(unsigned, f);
  u += 0x7fffu + ((u >> 16) & 1u);          // RNE
  return (unsigned short)(u >> 16);
}

// ---------------- prep: W[o,c,n] fp32 -> bf16 MFMA-A fragment order ----------------
// frag f = ((n*8+kc)*16+ot): lane l holds 8 bf16: W[ot*16+(l&15)][kc*32+(l>>4)*8+j][n]
__global__ void prep_w_kernel(const float* __restrict__ w, unsigned short* __restrict__ wp) {
  int t = blockIdx.x * 256 + threadIdx.x;   // 0..57343
  int l  = t & 63;
  int ot = (t >> 6) & 15;
  int kc = (t >> 10) & 7;
  int n  = t >> 13;
  int o  = ot * 16 + (l & 15);
  int cb = kc * 32 + ((l >> 4) * 8);
  const float* src = w + (size_t)(o * 256 + cb) * 7 + n;
  short8 pk;
#pragma unroll
  for (int j = 0; j < 8; ++j) pk[j] = (short)f2bf(src[j * 7]);
  ((short8*)wp)[t] = pk;
}

// ---------------- prep: zero only the pad rows of xb (compact) ----------------
__global__ void zero_pads5(unsigned short* __restrict__ xb) {
  int idx = blockIdx.x * 256 + threadIdx.x;   // 32*271*32 = 277,504 threads
  if (idx >= 32 * NPADROW * 32) return;
  int c16 = idx & 31;
  int rr  = idx >> 5;
  int pr  = rr % NPADROW;
  int b   = rr / NPADROW;
  int row;
  if (pr < 56)        row = pr;                          // leading apron
  else if (pr < 105)  row = 105 + 50 * (pr - 56);        // col-49 pad rows
  else                row = 2506 + (pr - 105);           // trailing apron
  short8 z = {0,0,0,0,0,0,0,0};
  *(short8*)(xb + ((size_t)b * XBROWS + row) * 256 + c16 * 8) = z;
}

// ---------------- prep: x [b][c][2401] fp32 -> xb [b][row][256c] bf16 (masked) ------
__global__ __launch_bounds__(256)
void prep_x4(const float* __restrict__ x, unsigned short* __restrict__ xb) {
  __shared__ unsigned short t[64][68];      // [ch_local][pix_local]
  const int tid = threadIdx.x;
  const int span = blockIdx.x, cg = blockIdx.y, b = blockIdx.z;
  const int s0 = span * 64;
  {
    const int chl = tid >> 2, i4 = tid & 3;
    const float* src = x + ((size_t)(b * 256 + cg * 64 + chl)) * NPIX;
    const int rbase = s0 + i4 * 16;
#pragma unroll
    for (int it = 0; it < 4; ++it) {
      int r = rbase + it * 4;
      float vv[4] = {0.f, 0.f, 0.f, 0.f};
      if (r + 3 < NPIX) {
        float4 v = *(const float4*)(src + r);
        vv[0] = v.x; vv[1] = v.y; vv[2] = v.z; vv[3] = v.w;
      } else {
#pragma unroll
        for (int e = 0; e < 4; ++e) if (r + e < NPIX) vv[e] = src[r + e];
      }
      short4v u = {0, 0, 0, 0};
#pragma unroll
      for (int e = 0; e < 4; ++e) {
        int re = r + e;
        unsigned short uu = 0;
        if (re < NPIX) {
          int h = re / 49, w = re - h * 49, s = h + w;
          if (s >= 24 && s <= 72) uu = f2bf(vv[e]);
        }
        u[e] = (short)uu;
      }
      *(short4v*)&t[chl][i4 * 16 + it * 4] = u;
    }
  }
  __syncthreads();
  const int pp = tid >> 3;   // pixel pair 0..31
  const int co = tid & 7;    // channel octet 0..7
  unsigned d[8];
#pragma unroll
  for (int k = 0; k < 8; ++k) d[k] = *(const unsigned*)&t[co * 8 + k][pp * 2];
  uint4 lo, hi;
  {
    unsigned l0[4], h0[4];
#pragma unroll
    for (int m = 0; m < 4; ++m) {
      unsigned a = d[2 * m], bq = d[2 * m + 1];
      l0[m] = (a & 0xffffu) | (bq << 16);
      h0[m] = (a >> 16) | (bq & 0xffff0000u);
    }
    lo = make_uint4(l0[0], l0[1], l0[2], l0[3]);
    hi = make_uint4(h0[0], h0[1], h0[2], h0[3]);
  }
  const int r_lo = s0 + pp * 2, r_hi = r_lo + 1;
  if (r_lo < NPIX) {
    int prow = r_lo + r_lo / 49 + XBLEAD;
    *(uint4*)(xb + ((size_t)b * XBROWS + prow) * 256 + cg * 64 + co * 8) = lo;
  }
  if (r_hi < NPIX) {
    int prow = r_hi + r_hi / 49 + XBLEAD;
    *(uint4*)(xb + ((size_t)b * XBROWS + prow) * 256 + cg * 64 + co * 8) = hi;
  }
}

// ---------------- main v8 ----------------
__global__ __launch_bounds__(256, 2)
void hexconv_v8(const unsigned short* __restrict__ xb,
                const unsigned short* __restrict__ wp,
                const float* __restrict__ bias,
                float* __restrict__ out) {
  __shared__ __attribute__((aligned(16))) unsigned char smem[2 * BUF6];  // 69632 B

  const int tid  = threadIdx.x;
  const int lane = tid & 63;
  const int wv   = tid >> 6;
  const int col  = lane & 15;
  const int quad = lane >> 4;

  const int pt = blockIdx.x;          // 0..15
  const int b  = blockIdx.y;
  const int P0 = pt * PT6;
  const int phase = ((pt + b) & 3) * 2;

  // tap offsets in pitch-50 padded space
  const int OFF[7] = {0, 50, 1, -49, -50, -1, 49};

  // B-frag LDS base addresses (kc/j-invariant), packed 16-bit pairs -> 4 regs.
  // Values: r0 in [6,121] -> addr < 8192, fits u16.
  unsigned pk[4];
  {
    int bav[7];
#pragma unroll
    for (int n = 0; n < 7; ++n) {
      int r0 = col + 56 + OFF[n];              // 6..121
      int r64 = r0 << 6;
      bav[n] = (r64 + quad * 16) ^ ((r64 >> 3) & 0x30);
    }
    pk[0] = (unsigned)bav[0] | ((unsigned)bav[1] << 16);
    pk[1] = (unsigned)bav[2] | ((unsigned)bav[3] << 16);
    pk[2] = (unsigned)bav[4] | ((unsigned)bav[5] << 16);
    pk[3] = (unsigned)bav[6];
  }

  // staging: within a seg, lane l covers row 16s+(l>>2), LDS part l&3 (HW-forced),
  // global part swizzled so compute-side XOR lands conflict-free
  const int gpart = (lane & 3) ^ ((lane >> 3) & 3);
  const char* gsrc0 = (const char*)(xb + ((size_t)b * XBROWS + (size_t)P0) * 256)
                      + (lane >> 2) * 512 + gpart * 16;

  // stage 2 kc into one buffer: 34 seg-units split over 4 waves
  auto stage2 = [&](int buf, int kc0) {
    char* ldsb = (char*)smem + buf * BUF6;
    for (int u = wv; u < 2 * NSEG6; u += 4) {
      int kk = (u >= NSEG6) ? 1 : 0;
      int s  = u - kk * NSEG6;
      __builtin_amdgcn_global_load_lds(
          (const __attribute__((address_space(1))) unsigned int*)
              (gsrc0 + (size_t)s * 8192 + (kc0 + kk) * 64),
          (__attribute__((address_space(3))) unsigned int*)(ldsb + u * 1024), 16, 0, 0);
    }
  };

  const char* wbase = (const char*)wp + (size_t)(wv * 4) * 1024 + lane * 16;

  floatx4 acc[4][10];
#pragma unroll
  for (int ii = 0; ii < 4; ++ii)
#pragma unroll
    for (int j = 0; j < 10; ++j) acc[ii][j] = (floatx4){0.f, 0.f, 0.f, 0.f};

  stage2(0, phase);
  __syncthreads();

  for (int i = 0; i < 4; ++i) {
    const int kc0  = (2 * i + phase) & 7;
    const int kc0n = (2 * i + 2 + phase) & 7;
    if (i < 3) stage2((i + 1) & 1, kc0n);
    const char* bufp = (const char*)smem + (i & 1) * BUF6;
#pragma unroll
    for (int n = 0; n < 7; ++n) {
      const int ban = (n & 1) ? (int)(pk[n >> 1] >> 16) : (int)(pk[n >> 1] & 0xffffu);
#pragma unroll
      for (int kk = 0; kk < 2; ++kk) {
        const int kc = kc0 + kk;
        short8 af[4];
#pragma unroll
        for (int ii = 0; ii < 4; ++ii)
          af[ii] = *(const short8*)(wbase + ((size_t)((n * 8 + kc) * 16 + ii)) * 1024);
        const char* bp = bufp + kk * (NSEG6 * 1024) + ban;
#pragma unroll
        for (int j = 0; j < 10; ++j) {
          short8 bf = *(const short8*)(bp + j * 1024);
#pragma unroll
          for (int ii = 0; ii < 4; ++ii)
            acc[ii][j] = __builtin_amdgcn_mfma_f32_16x16x32_bf16(af[ii], bf, acc[ii][j], 0, 0, 0);
        }
      }
    }
    if (i < 3) __syncthreads();
  }

  // epilogue: pre-add bias into acc (bv regs die before store addressing),
  // then store with 32-bit index math. o = wv*64+ii*16+quad*4+rr,
  // padded pix = P0+j*16+col.  Result is bitwise-identical to v6's
  // (m ? acc+bv : 0) since the select happens after the add either way.
  const int ob = wv * 64;
#pragma unroll
  for (int ii = 0; ii < 4; ++ii) {
    floatx4 bv = *(const floatx4*)(bias + ob + ii * 16 + quad * 4);
#pragma unroll
    for (int j = 0; j < 10; ++j)
#pragma unroll
      for (int rr = 0; rr < 4; ++rr) acc[ii][j][rr] += bv[rr];
  }

#pragma unroll
  for (int j = 0; j < 10; ++j) {
    int p = P0 + j * 16 + col;
    int h = p / W50;
    int w = p - h * W50;
    if (w >= 49 || p >= PREAL) continue;
    bool m = (h + w >= 24) && (h + w <= 72);
    int ridx = h * 49 + w;
#pragma unroll
    for (int ii = 0; ii < 4; ++ii) {
      int base = (b * 256 + ob + ii * 16 + quad * 4) * NPIX + ridx;  // < 2^31
      float* dst = out + base;
#pragma unroll
      for (int rr = 0; rr < 4; ++rr) {
        float v = m ? acc[ii][j][rr] : 0.f;
        dst[rr * NPIX] = v;
      }
    }
  }
}

// ---------------- fallback v1 (ws too small) ----------------
#define PITCH  40
#define V1WIN  168
#define V1ZROW 168
__global__ __launch_bounds__(256)
void hexconv_v1(const float* __restrict__ x,
                const unsigned short* __restrict__ wp,
                const float* __restrict__ bias,
                float* __restrict__ out) {
  __shared__ unsigned short sm[(V1ZROW + 2) * PITCH];
  const int tid = threadIdx.x, lane = tid & 63, wv = tid >> 6;
  const int col = lane & 15, quad = lane >> 4;
  const int pt = blockIdx.x, b = blockIdx.y;
  const int P0 = pt * 64, win_start = P0 - 52;
  if (tid < PITCH * 2) sm[V1ZROW * PITCH + tid] = 0;
  const int OFF[7] = {0, 49, 1, -48, -49, -1, 48};
  const int DXP = (1 << 2) | (1 << 3), DXN = (1 << 5) | (1 << 6);
  int baddr[4][7];
#pragma unroll
  for (int j = 0; j < 4; ++j) {
    int pix = P0 + j * 16 + col;
    int wj = pix % 49;
    int rowbase = pix - win_start;
#pragma unroll
    for (int n = 0; n < 7; ++n) {
      bool bad = (((DXP >> n) & 1) && wj == 48) || (((DXN >> n) & 1) && wj == 0);
      int row = bad ? V1ZROW : (rowbase + OFF[n]);
      baddr[j][n] = row * (PITCH * 2) + quad * 16;
    }
  }
  int sp[3], sgp[3]; bool sok[3];
#pragma unroll
  for (int pi = 0; pi < 3; ++pi) {
    int p = lane + pi * 64, gp = win_start + p;
    sp[pi] = p; sgp[pi] = gp;
    bool hm = false;
    if (gp >= 0 && gp < NPIX) { int h = gp / 49, w = gp - h * 49, s = h + w; hm = (s >= 24 && s <= 72); }
    sok[pi] = (p < V1WIN) && hm;
  }
  floatx4 acc[4][4];
#pragma unroll
  for (int i = 0; i < 4; ++i)
#pragma unroll
    for (int j = 0; j < 4; ++j) acc[i][j] = (floatx4){0.f, 0.f, 0.f, 0.f};
  const short8* wpv = (const short8*)wp;
  const int wslot = wv * 4;
  for (int kc = 0; kc < 8; ++kc) {
    __syncthreads();
#pragma unroll
    for (int ci = 0; ci < 8; ++ci) {
      int c = ci * 4 + wv;
      const float* src = x + ((size_t)(b * 256 + kc * 32 + c)) * NPIX;
#pragma unroll
      for (int pi = 0; pi < 3; ++pi) {
        if (sp[pi] < V1WIN) {
          float v = sok[pi] ? src[sgp[pi]] : 0.f;
          sm[sp[pi] * PITCH + c] = f2bf(v);
        }
      }
    }
    __syncthreads();
#pragma unroll
    for (int n = 0; n < 7; ++n) {
      short8 af[4];
#pragma unroll
      for (int i = 0; i < 4; ++i)
        af[i] = wpv[((size_t)((n * 8 + kc) * 16 + wslot + i)) * 64 + lane];
      short8 bf[4];
#pragma unroll
      for (int j = 0; j < 4; ++j)
        bf[j] = *(const short8*)((const char*)sm + baddr[j][n]);
#pragma unroll
      for (int i = 0; i < 4; ++i)
#pragma unroll
        for (int j = 0; j < 4; ++j)
          acc[i][j] = __builtin_amdgcn_mfma_f32_16x16x32_bf16(af[i], bf[j], acc[i][j], 0, 0, 0);
    }
  }
  const int ob = wv * 64;
  floatx4 bv[4];
#pragma unroll
  for (int i = 0; i < 4; ++i)
    bv[i] = *(const floatx4*)(bias + ob + i * 16 + quad * 4);
#pragma unroll
  for (int j = 0; j < 4; ++j) {
    int pix = P0 + j * 16 + col;
    if (pix >= NPIX) continue;
    int h = pix / 49, w = pix - h * 49;
    bool m = (h + w >= 24 && h + w <= 72);
#pragma unroll
    for (int i = 0; i < 4; ++i) {
      int o = ob + i * 16 + quad * 4;
      float* dst = out + ((size_t)(b * 256 + o)) * NPIX + pix;
#pragma unroll
      for (int r = 0; r < 4; ++r) {
        float v = m ? (acc[i][j][r] + bv[i][r]) : 0.f;
        dst[(size_t)r * NPIX] = v;
      }
    }
  }
}

extern "C" void kernel_launch(void* const* d_in, const int* in_sizes, int n_in,
                              void* d_out, int out_size, void* d_ws, size_t ws_size,
                              hipStream_t stream) {
  const float* x    = (const float*)d_in[0];   // [32,256,49,49]
  const float* w    = (const float*)d_in[1];   // [256,256,7]
  const float* bias = (const float*)d_in[2];   // [256]
  float* out = (float*)d_out;

  if (ws_size >= WS_NEED3) {
    unsigned short* xb = (unsigned short*)d_ws;
    unsigned short* wp = (unsigned short*)((char*)d_ws + XB3_BYTES);
    zero_pads5<<<(32 * NPADROW * 32 + 255) / 256, 256, 0, stream>>>(xb);
    prep_w_kernel<<<224, 256, 0, stream>>>(w, wp);
    prep_x4<<<dim3(38, 4, 32), 256, 0, stream>>>(x, xb);
    hexconv_v8<<<dim3(NT6, 32), 256, 0, stream>>>(xb, wp, bias, out);
  } else {
    unsigned short* wp = (unsigned short*)d_ws;
    prep_w_kernel<<<224, 256, 0, stream>>>(w, wp);
    hexconv_v1<<<dim3(38, 32), 256, 0, stream>>>(x, wp, bias, out);
  }
}